// Round 1
// baseline (360.942 us; speedup 1.0000x reference)
//
#include <hip/hip_runtime.h>
#include <math.h>

#define N_VOX 262144      // 64^3
#define BIGF  1e8f
#define NB    4           // batch
#define NC    4           // classes

// ---- accumulator layout (doubles in d_ws, offset 0) ----
// [0..15]  inter[b*4+c]
// [16..31] sum_probs[b*4+c]
// [32..47] count[b*4+c]
// [48]     ce_sum
// [49..60] bound_sum[combo], combo = b*3 + (c-1), c in 1..3
#define ACC_DOUBLES 61

__global__ void init_acc(double* acc) {
    int t = threadIdx.x;
    if (t < ACC_DOUBLES) acc[t] = 0.0;
}

// Fused softmax stats: dice partial sums, CE sum, and EDT init buffers.
// grid = B*N_VOX/256 = 4096 blocks of 256. Each block covers 256 voxels of one b.
__global__ void stats_kernel(const float* __restrict__ preds,
                             const int* __restrict__ targets,
                             float* __restrict__ bufA,
                             double* __restrict__ acc) {
    int g = blockIdx.x * 256 + threadIdx.x;   // [0, 4*262144)
    int b = g >> 18;
    int v = g & (N_VOX - 1);
    const float* p = preds + (size_t)(b * NC) * N_VOX + v;
    float x0 = p[0];
    float x1 = p[N_VOX];
    float x2 = p[2 * N_VOX];
    float x3 = p[3 * N_VOX];
    float m  = fmaxf(fmaxf(x0, x1), fmaxf(x2, x3));
    float e0 = expf(x0 - m), e1 = expf(x1 - m), e2 = expf(x2 - m), e3 = expf(x3 - m);
    float ssum = e0 + e1 + e2 + e3;
    float inv  = 1.0f / ssum;
    float p0 = e0 * inv, p1 = e1 * inv, p2 = e2 * inv, p3 = e3 * inv;

    int t = targets[g];
    float xt = (t == 0) ? x0 : (t == 1) ? x1 : (t == 2) ? x2 : x3;
    float neg_logp = -(xt - m - logf(ssum));

    // EDT init buffers for c=1..3: [combo] = mask?0:BIG, [combo+12] = mask?BIG:0
    #pragma unroll
    for (int c = 1; c < NC; ++c) {
        int combo = b * 3 + (c - 1);
        bool is = (t == c);
        bufA[(size_t)combo * N_VOX + v]        = is ? 0.0f : BIGF;
        bufA[(size_t)(combo + 12) * N_VOX + v] = is ? BIGF : 0.0f;
    }

    // 13 per-thread quantities
    float q[13];
    q[0] = (t == 0) ? p0 : 0.0f;
    q[1] = (t == 1) ? p1 : 0.0f;
    q[2] = (t == 2) ? p2 : 0.0f;
    q[3] = (t == 3) ? p3 : 0.0f;
    q[4] = p0; q[5] = p1; q[6] = p2; q[7] = p3;
    q[8]  = (t == 0) ? 1.0f : 0.0f;
    q[9]  = (t == 1) ? 1.0f : 0.0f;
    q[10] = (t == 2) ? 1.0f : 0.0f;
    q[11] = (t == 3) ? 1.0f : 0.0f;
    q[12] = neg_logp;

    // wave (64-lane) shuffle reduce
    #pragma unroll
    for (int k = 0; k < 13; ++k) {
        float x = q[k];
        #pragma unroll
        for (int o = 32; o > 0; o >>= 1) x += __shfl_down(x, o);
        q[k] = x;
    }

    __shared__ float sacc[13];
    if (threadIdx.x < 13) sacc[threadIdx.x] = 0.0f;
    __syncthreads();
    if ((threadIdx.x & 63) == 0) {
        #pragma unroll
        for (int k = 0; k < 13; ++k) atomicAdd(&sacc[k], q[k]);
    }
    __syncthreads();
    if (threadIdx.x < 13) {
        int k = threadIdx.x;
        int gi;
        if (k < 4)       gi = b * 4 + k;            // inter
        else if (k < 8)  gi = 16 + b * 4 + (k - 4); // sum_probs
        else if (k < 12) gi = 32 + b * 4 + (k - 8); // count
        else             gi = 48;                    // ce
        atomicAdd(&acc[gi], (double)sacc[k]);
    }
}

// One in-place min-plus EDT pass along one axis.
// 24 volumes of 64^3; 4096 lines/volume, 64 elems/line, element stride s.
// base(l) = (l / P) * A + (l % P) * Bm  (+ vol*N_VOX)
// grid = 24*4096/4 = 24576 blocks of 256 (4 lines per block).
__global__ void edt_pass(float* __restrict__ buf, int P, int A, int Bm, int s) {
    __shared__ float lds[4][65];   // +1 pad: avoid 4-way bank conflict in s!=1 mapping
    int t  = threadIdx.x;
    int li, j;
    if (s == 1) { li = t >> 6; j = t & 63; }   // wave-per-line, coalesced
    else        { li = t & 3;  j = t >> 2; }   // 4 adjacent lines contiguous in mem
    int gl  = blockIdx.x * 4 + li;             // global line id
    int vol = gl >> 12;
    int l   = gl & 4095;
    size_t base = (size_t)vol * N_VOX + (size_t)(l / P) * A + (size_t)(l % P) * Bm;
    lds[li][j] = buf[base + (size_t)j * s];
    __syncthreads();
    float jf = (float)j;
    float d0 = jf;                      // j - 0
    float best = lds[li][0] + d0 * d0;
    #pragma unroll
    for (int k = 1; k < 64; ++k) {
        float d = jf - (float)k;
        float cand = lds[li][k] + d * d;
        best = fminf(best, cand);
    }
    buf[base + (size_t)j * s] = best;
}

// sdf = sqrt(dout2) - sqrt(din2); accumulate sdf * prob_c per combo.
// grid = 12*N_VOX/256 = 12288 blocks; each block one combo.
__global__ void sdf_kernel(const float* __restrict__ preds,
                           const float* __restrict__ bufA,
                           double* __restrict__ acc) {
    int g = blockIdx.x * 256 + threadIdx.x;   // [0, 12*N_VOX)
    int combo = g >> 18;
    int v = g & (N_VOX - 1);
    int b = combo / 3;
    int c = (combo % 3) + 1;
    float dout2 = bufA[(size_t)combo * N_VOX + v];
    float din2  = bufA[(size_t)(combo + 12) * N_VOX + v];
    float sdf = sqrtf(dout2) - sqrtf(din2);
    const float* p = preds + (size_t)(b * NC) * N_VOX + v;
    float x0 = p[0];
    float x1 = p[N_VOX];
    float x2 = p[2 * N_VOX];
    float x3 = p[3 * N_VOX];
    float m  = fmaxf(fmaxf(x0, x1), fmaxf(x2, x3));
    float e0 = expf(x0 - m), e1 = expf(x1 - m), e2 = expf(x2 - m), e3 = expf(x3 - m);
    float ssum = e0 + e1 + e2 + e3;
    float ec = (c == 1) ? e1 : (c == 2) ? e2 : e3;
    float val = sdf * (ec / ssum);

    #pragma unroll
    for (int o = 32; o > 0; o >>= 1) val += __shfl_down(val, o);
    __shared__ float sacc;
    if (threadIdx.x == 0) sacc = 0.0f;
    __syncthreads();
    if ((threadIdx.x & 63) == 0) atomicAdd(&sacc, val);
    __syncthreads();
    if (threadIdx.x == 0) atomicAdd(&acc[49 + combo], (double)sacc);
}

__global__ void final_kernel(const double* __restrict__ acc, float* __restrict__ out) {
    if (threadIdx.x != 0 || blockIdx.x != 0) return;
    const double NV = (double)N_VOX;
    double dice_sum = 0.0;
    for (int i = 0; i < 16; ++i) {
        double inter = acc[i];
        double un    = acc[16 + i] + acc[32 + i];
        dice_sum += (2.0 * inter + 1e-5) / (un + 1e-5);
    }
    double l_dice = 1.0 - dice_sum / 16.0;
    double l_ce = acc[48] / (4.0 * NV);
    double lb = 0.0;
    for (int combo = 0; combo < 12; ++combo) {
        int b = combo / 3;
        int c = combo % 3 + 1;
        double cnt = acc[32 + b * 4 + c];
        double s;
        if (cnt == 0.0)      s =  acc[16 + b * 4 + c];  // sdf == +1 everywhere
        else if (cnt == NV)  s = -acc[16 + b * 4 + c];  // sdf == -1 everywhere
        else                 s =  acc[49 + combo];
        lb += s / NV;
    }
    lb /= 12.0;
    out[0] = (float)(l_dice + l_ce + 0.01 * lb);
}

extern "C" void kernel_launch(void* const* d_in, const int* in_sizes, int n_in,
                              void* d_out, int out_size, void* d_ws, size_t ws_size,
                              hipStream_t stream) {
    const float* preds   = (const float*)d_in[0];
    const int*   targets = (const int*)d_in[1];
    float* out = (float*)d_out;

    double* acc = (double*)d_ws;
    float* bufA = (float*)((char*)d_ws + 512);   // 24 volumes * 64^3 floats = 24 MiB

    init_acc<<<1, 64, 0, stream>>>(acc);
    stats_kernel<<<(NB * N_VOX) / 256, 256, 0, stream>>>(preds, targets, bufA, acc);
    // 3 in-place min-plus passes: W (stride 1), H (stride 64), D (stride 4096)
    edt_pass<<<24 * 4096 / 4, 256, 0, stream>>>(bufA, 4096, 0, 64, 1);
    edt_pass<<<24 * 4096 / 4, 256, 0, stream>>>(bufA, 64, 4096, 1, 64);
    edt_pass<<<24 * 4096 / 4, 256, 0, stream>>>(bufA, 4096, 0, 1, 4096);
    sdf_kernel<<<(12 * N_VOX) / 256, 256, 0, stream>>>(preds, bufA, acc);
    final_kernel<<<1, 64, 0, stream>>>(acc, out);
}

// Round 2
// 91.017 us; speedup vs baseline: 3.9656x; 3.9656x over previous
//
#include <hip/hip_runtime.h>
#include <hip/hip_bf16.h>
#include <math.h>

#define NVOX 262144   // 64^3
#define BIGF 1e8f

// ---- helpers ----
__device__ __forceinline__ unsigned short f2bf(float x) {
    __hip_bfloat16 h = __float2bfloat16(x);
    return *reinterpret_cast<unsigned short*>(&h);
}
__device__ __forceinline__ float bf2f(unsigned short u) {
    __hip_bfloat16 h = *reinterpret_cast<__hip_bfloat16*>(&u);
    return __bfloat162float(h);
}
// squared distance (as u16, 0xFFFF = +inf) from lane w to nearest set bit of mask
__device__ __forceinline__ unsigned short dist2_u16(unsigned long long mask, int w) {
    if (mask == 0ull) return 0xFFFFu;
    unsigned long long mr = mask >> w;          // bits k >= w  (bit0 => dist 0)
    unsigned long long ml = mask << (63 - w);   // bits k <= w  (bit63 => dist 0)
    int dr = mr ? __builtin_ctzll(mr) : 127;
    int dl = ml ? __builtin_clzll(ml) : 127;
    int dd = dr < dl ? dr : dl;
    return (unsigned short)(dd * dd);
}

// =====================================================================
// K1: block = (b, d-slice). Softmax stats (dice/CE partials), transposed
// bf16 probs, and ballot-based pass-1 (W axis) EDT init, transposed u16.
// Layouts written:
//   probsT[b*3+c-1][w][d*64+h]  (bf16)
//   bufA [combo(=b*3+c-1) + 12*inout][w][d*64+h]  (u16 squared dist, 0xFFFF=BIG)
// =====================================================================
__global__ __launch_bounds__(512) void k1_stats_edt1(
    const float* __restrict__ preds, const int* __restrict__ targets,
    unsigned short* __restrict__ bufA, unsigned short* __restrict__ probsT,
    float* __restrict__ part_stats) {
    __shared__ int tgt[64 * 65];
    __shared__ unsigned short tiles[3 * 64 * 65];   // probs p1..p3, then reused as dout/din
    __shared__ float sred[8 * 13];

    int blk = blockIdx.x;
    int b = blk >> 6, d = blk & 63;
    int t = threadIdx.x, lane = t & 63, wid = t >> 6;
    size_t tbase = (size_t)b * NVOX + (size_t)d * 4096;
    size_t pbase = (size_t)(b * 4) * NVOX + (size_t)d * 4096;

    float q[13];
    #pragma unroll
    for (int k = 0; k < 13; ++k) q[k] = 0.0f;

    for (int i = 0; i < 8; ++i) {
        int e = t + 512 * i;
        int h = e >> 6, w = e & 63;
        int tv = targets[tbase + e];
        tgt[h * 65 + w] = tv;
        float x0 = preds[pbase + e];
        float x1 = preds[pbase + NVOX + e];
        float x2 = preds[pbase + 2 * NVOX + e];
        float x3 = preds[pbase + 3 * NVOX + e];
        float m  = fmaxf(fmaxf(x0, x1), fmaxf(x2, x3));
        float e0 = expf(x0 - m), e1 = expf(x1 - m), e2 = expf(x2 - m), e3 = expf(x3 - m);
        float ssum = e0 + e1 + e2 + e3;
        float inv  = 1.0f / ssum;
        float p0 = e0 * inv, p1 = e1 * inv, p2 = e2 * inv, p3 = e3 * inv;
        float xt = (tv == 0) ? x0 : (tv == 1) ? x1 : (tv == 2) ? x2 : x3;
        q[12] += -(xt - m - logf(ssum));
        q[4] += p0; q[5] += p1; q[6] += p2; q[7] += p3;
        if (tv == 0)      { q[0] += p0; q[8]  += 1.0f; }
        else if (tv == 1) { q[1] += p1; q[9]  += 1.0f; }
        else if (tv == 2) { q[2] += p2; q[10] += 1.0f; }
        else              { q[3] += p3; q[11] += 1.0f; }
        int li = h * 65 + w;
        tiles[li]            = f2bf(p1);
        tiles[4160 + li]     = f2bf(p2);
        tiles[2 * 4160 + li] = f2bf(p3);
    }

    // block-reduce the 13 stats partials (no atomics anywhere)
    #pragma unroll
    for (int k = 0; k < 13; ++k) {
        float x = q[k];
        #pragma unroll
        for (int o = 32; o > 0; o >>= 1) x += __shfl_down(x, o);
        if (lane == 0) sred[wid * 13 + k] = x;
    }
    __syncthreads();   // also guarantees tgt + prob tiles complete
    if (t < 13) {
        float s = 0.0f;
        for (int j = 0; j < 8; ++j) s += sred[j * 13 + t];
        part_stats[t * 256 + blk] = s;
    }

    // transposed probsT writes: lane = h (coalesced 128B/wave), wave strides w
    for (int c = 0; c < 3; ++c) {
        size_t obase = (size_t)(b * 3 + c) * NVOX + (size_t)d * 64;
        for (int w = wid; w < 64; w += 8)
            probsT[obase + (size_t)w * 4096 + lane] = tiles[c * 4160 + lane * 65 + w];
    }
    __syncthreads();   // before reusing tiles

    // ballot pass-1 per class: wave = one W-line (lane = w)
    unsigned short* tA = tiles;
    unsigned short* tB = tiles + 4160;
    for (int c = 1; c <= 3; ++c) {
        for (int r = 0; r < 8; ++r) {
            int row = wid * 8 + r;      // = h
            int tv = tgt[row * 65 + lane];
            unsigned long long mask = __ballot(tv == c);
            tA[row * 65 + lane] = dist2_u16(mask, lane);     // d_out^2 (1D)
            tB[row * 65 + lane] = dist2_u16(~mask, lane);    // d_in^2  (1D)
        }
        __syncthreads();
        int combo = b * 3 + c - 1;
        size_t oA = (size_t)combo * NVOX + (size_t)d * 64;
        size_t oB = (size_t)(combo + 12) * NVOX + (size_t)d * 64;
        for (int w = wid; w < 64; w += 8) {
            bufA[oA + (size_t)w * 4096 + lane] = tA[lane * 65 + w];
            bufA[oB + (size_t)w * 4096 + lane] = tB[lane * 65 + w];
        }
        __syncthreads();
    }
}

// =====================================================================
// K2: block = (combo, w). Loads the two (d,h) planes (out/in) contiguously,
// does min-plus passes along H then D fully in LDS, then reduces
// (sqrt(dout2)-sqrt(din2)) * prob_c with coalesced bf16 prob reads.
// =====================================================================
__global__ __launch_bounds__(512) void k2_edt23_sdf(
    const unsigned short* __restrict__ bufA, const unsigned short* __restrict__ probsT,
    float* __restrict__ part_bound) {
    __shared__ float pl[2][64 * 65];
    __shared__ float sredb[8];
    int blk = blockIdx.x;
    int combo = blk >> 6, w = blk & 63;
    int t = threadIdx.x, lane = t & 63, wid = t >> 6;

    for (int v = 0; v < 2; ++v) {
        const unsigned short* src = bufA + (size_t)(combo + 12 * v) * NVOX + (size_t)w * 4096;
        for (int i = 0; i < 8; ++i) {
            int e = t + 512 * i;                     // e = d*64 + h
            unsigned short u = src[e];
            pl[v][e + (e >> 6)] = (u == 0xFFFFu) ? BIGF : (float)u;   // lds[d*65+h]
        }
    }
    __syncthreads();

    float hf = (float)lane;
    // pass along H: wave owns rows d = wid*8+r, lane = h; broadcast row reads
    for (int v = 0; v < 2; ++v) {
        for (int r = 0; r < 8; ++r) {
            int dd = wid * 8 + r;
            const float* row = &pl[v][dd * 65];
            float ba = row[0] + hf * hf;             // k = 0
            float bb = BIGF * 2.0f;
            #pragma unroll
            for (int k = 1; k < 64; k += 2) {        // two chains to break fmin dependency
                float d1 = hf - (float)k;
                ba = fminf(ba, fmaf(d1, d1, row[k]));
                float d2 = hf - (float)(k + 1);
                bb = fminf(bb, fmaf(d2, d2, row[k + 1]));
            }
            float best = fminf(ba, bb);
            pl[v][dd * 65 + lane] = best;            // in-place: all reads done (lockstep)
        }
    }
    __syncthreads();
    // pass along D: wave owns columns h = wid*8+r, lane = d; broadcast column reads
    for (int v = 0; v < 2; ++v) {
        for (int r = 0; r < 8; ++r) {
            int h = wid * 8 + r;
            float ba = pl[v][h] + hf * hf;           // k = 0
            float bb = BIGF * 2.0f;
            #pragma unroll
            for (int k = 1; k < 64; k += 2) {
                float d1 = hf - (float)k;
                ba = fminf(ba, fmaf(d1, d1, pl[v][k * 65 + h]));
                float d2 = hf - (float)(k + 1);
                bb = fminf(bb, fmaf(d2, d2, pl[v][(k + 1) * 65 + h]));
            }
            float best = fminf(ba, bb);
            pl[v][lane * 65 + h] = best;             // stride-65 write: conflict-free
        }
    }
    __syncthreads();

    const unsigned short* pp = probsT + (size_t)combo * NVOX + (size_t)w * 4096;
    float acc = 0.0f;
    for (int i = 0; i < 8; ++i) {
        int e = t + 512 * i;
        int li = e + (e >> 6);
        float sdf = sqrtf(pl[0][li]) - sqrtf(pl[1][li]);
        acc += sdf * bf2f(pp[e]);
    }
    #pragma unroll
    for (int o = 32; o > 0; o >>= 1) acc += __shfl_down(acc, o);
    if (lane == 0) sredb[wid] = acc;
    __syncthreads();
    if (t == 0) {
        float s = 0.0f;
        for (int j = 0; j < 8; ++j) s += sredb[j];
        part_bound[blk] = s;
    }
}

// =====================================================================
// K3: single block. Reduce partials (f64), apply empty/full-mask guards,
// assemble the scalar loss.
// =====================================================================
__global__ __launch_bounds__(1024) void k3_final(
    const float* __restrict__ part_stats, const float* __restrict__ part_bound,
    float* __restrict__ out) {
    __shared__ double S[13 * 4];
    __shared__ double BND[12];
    int t = threadIdx.x, lane = t & 63, wid = t >> 6;

    if (t < 256) {              // waves 0..3 <-> b; 64 d-blocks per b
        for (int k = 0; k < 13; ++k) {
            float v = part_stats[k * 256 + t];
            #pragma unroll
            for (int o = 32; o > 0; o >>= 1) v += __shfl_down(v, o);
            if (lane == 0) S[k * 4 + wid] = (double)v;
        }
    }
    __syncthreads();
    if (t < 768) {              // wave id = combo (64 w-entries each)
        float v = part_bound[t];
        #pragma unroll
        for (int o = 32; o > 0; o >>= 1) v += __shfl_down(v, o);
        if (lane == 0) BND[wid] = (double)v;
    }
    __syncthreads();
    if (t == 0) {
        const double NV = (double)NVOX;
        double dice_sum = 0.0;
        for (int b = 0; b < 4; ++b)
            for (int c = 0; c < 4; ++c) {
                double inter = S[c * 4 + b];
                double un    = S[(4 + c) * 4 + b] + S[(8 + c) * 4 + b];
                dice_sum += (2.0 * inter + 1e-5) / (un + 1e-5);
            }
        double l_dice = 1.0 - dice_sum / 16.0;
        double l_ce = (S[48] + S[49] + S[50] + S[51]) / (4.0 * NV);
        double lb = 0.0;
        for (int combo = 0; combo < 12; ++combo) {
            int b = combo / 3, c = combo % 3 + 1;
            double cnt = S[(8 + c) * 4 + b];
            double s;
            if (cnt == 0.0)      s =  S[(4 + c) * 4 + b];   // sdf == +1 everywhere
            else if (cnt == NV)  s = -S[(4 + c) * 4 + b];   // sdf == -1 everywhere
            else                 s =  BND[combo];
            lb += s / NV;
        }
        lb /= 12.0;
        out[0] = (float)(l_dice + l_ce + 0.01 * lb);
    }
}

extern "C" void kernel_launch(void* const* d_in, const int* in_sizes, int n_in,
                              void* d_out, int out_size, void* d_ws, size_t ws_size,
                              hipStream_t stream) {
    const float* preds   = (const float*)d_in[0];
    const int*   targets = (const int*)d_in[1];
    float* out = (float*)d_out;

    // workspace: bufA u16 (12.6 MB) | probsT bf16 (6.3 MB) | partials (~16 KB)
    unsigned short* bufA   = (unsigned short*)d_ws;
    unsigned short* probsT = bufA + (size_t)24 * NVOX;
    float* part_stats = (float*)(probsT + (size_t)12 * NVOX);
    float* part_bound = part_stats + 13 * 256;

    k1_stats_edt1<<<256, 512, 0, stream>>>(preds, targets, bufA, probsT, part_stats);
    k2_edt23_sdf<<<768, 512, 0, stream>>>(bufA, probsT, part_bound);
    k3_final<<<1, 1024, 0, stream>>>(part_stats, part_bound, out);
}

// Round 3
// 51.493 us; speedup vs baseline: 7.0095x; 1.7676x over previous
//
#include <hip/hip_runtime.h>
#include <hip/hip_bf16.h>
#include <math.h>

#define NVOX 262144   // 64^3
#define BIGF 1e8f

// ---- helpers ----
__device__ __forceinline__ unsigned short f2bf(float x) {
    __hip_bfloat16 h = __float2bfloat16(x);
    return *reinterpret_cast<unsigned short*>(&h);
}
__device__ __forceinline__ float bf2f(unsigned short u) {
    __hip_bfloat16 h = *reinterpret_cast<__hip_bfloat16*>(&u);
    return __bfloat162float(h);
}
// squared distance (as u16, 0xFFFF = +inf) from lane w to nearest set bit of mask
__device__ __forceinline__ unsigned short dist2_u16(unsigned long long mask, int w) {
    if (mask == 0ull) return 0xFFFFu;
    unsigned long long mr = mask >> w;          // bits k >= w  (bit0 => dist 0)
    unsigned long long ml = mask << (63 - w);   // bits k <= w  (bit63 => dist 0)
    int dr = mr ? __builtin_ctzll(mr) : 127;
    int dl = ml ? __builtin_clzll(ml) : 127;
    int dd = dr < dl ? dr : dl;
    return (unsigned short)(dd * dd);
}

// =====================================================================
// K1: block = (b, d-slice). Softmax stats (dice/CE partials), transposed
// bf16 probs, and ballot-based pass-1 (W axis) EDT init, transposed u16.
// Layouts written:
//   probsT[b*3+c-1][w][d*64+h]  (bf16)
//   bufA [combo(=b*3+c-1) + 12*inout][w][d*64+h]  (u16 squared dist, 0xFFFF=BIG)
// =====================================================================
__global__ __launch_bounds__(512) void k1_stats_edt1(
    const float* __restrict__ preds, const int* __restrict__ targets,
    unsigned short* __restrict__ bufA, unsigned short* __restrict__ probsT,
    float* __restrict__ part_stats) {
    __shared__ int tgt[64 * 65];
    __shared__ unsigned short tiles[3 * 64 * 65];   // probs p1..p3, then reused as dout/din
    __shared__ float sred[8 * 13];

    int blk = blockIdx.x;
    int b = blk >> 6, d = blk & 63;
    int t = threadIdx.x, lane = t & 63, wid = t >> 6;
    size_t tbase = (size_t)b * NVOX + (size_t)d * 4096;
    size_t pbase = (size_t)(b * 4) * NVOX + (size_t)d * 4096;

    float q[13];
    #pragma unroll
    for (int k = 0; k < 13; ++k) q[k] = 0.0f;

    for (int i = 0; i < 8; ++i) {
        int e = t + 512 * i;
        int h = e >> 6, w = e & 63;
        int tv = targets[tbase + e];
        tgt[h * 65 + w] = tv;
        float x0 = preds[pbase + e];
        float x1 = preds[pbase + NVOX + e];
        float x2 = preds[pbase + 2 * NVOX + e];
        float x3 = preds[pbase + 3 * NVOX + e];
        float m  = fmaxf(fmaxf(x0, x1), fmaxf(x2, x3));
        float e0 = expf(x0 - m), e1 = expf(x1 - m), e2 = expf(x2 - m), e3 = expf(x3 - m);
        float ssum = e0 + e1 + e2 + e3;
        float inv  = 1.0f / ssum;
        float p0 = e0 * inv, p1 = e1 * inv, p2 = e2 * inv, p3 = e3 * inv;
        float xt = (tv == 0) ? x0 : (tv == 1) ? x1 : (tv == 2) ? x2 : x3;
        q[12] += -(xt - m - logf(ssum));
        q[4] += p0; q[5] += p1; q[6] += p2; q[7] += p3;
        if (tv == 0)      { q[0] += p0; q[8]  += 1.0f; }
        else if (tv == 1) { q[1] += p1; q[9]  += 1.0f; }
        else if (tv == 2) { q[2] += p2; q[10] += 1.0f; }
        else              { q[3] += p3; q[11] += 1.0f; }
        int li = h * 65 + w;
        tiles[li]            = f2bf(p1);
        tiles[4160 + li]     = f2bf(p2);
        tiles[2 * 4160 + li] = f2bf(p3);
    }

    // block-reduce the 13 stats partials (no atomics anywhere)
    #pragma unroll
    for (int k = 0; k < 13; ++k) {
        float x = q[k];
        #pragma unroll
        for (int o = 32; o > 0; o >>= 1) x += __shfl_down(x, o);
        if (lane == 0) sred[wid * 13 + k] = x;
    }
    __syncthreads();   // also guarantees tgt + prob tiles complete
    if (t < 13) {
        float s = 0.0f;
        for (int j = 0; j < 8; ++j) s += sred[j * 13 + t];
        part_stats[t * 256 + blk] = s;
    }

    // transposed probsT writes: lane = h (coalesced 128B/wave), wave strides w
    for (int c = 0; c < 3; ++c) {
        size_t obase = (size_t)(b * 3 + c) * NVOX + (size_t)d * 64;
        for (int w = wid; w < 64; w += 8)
            probsT[obase + (size_t)w * 4096 + lane] = tiles[c * 4160 + lane * 65 + w];
    }
    __syncthreads();   // before reusing tiles

    // ballot pass-1 per class: wave = one W-line (lane = w)
    unsigned short* tA = tiles;
    unsigned short* tB = tiles + 4160;
    for (int c = 1; c <= 3; ++c) {
        for (int r = 0; r < 8; ++r) {
            int row = wid * 8 + r;      // = h
            int tv = tgt[row * 65 + lane];
            unsigned long long mask = __ballot(tv == c);
            tA[row * 65 + lane] = dist2_u16(mask, lane);     // d_out^2 (1D)
            tB[row * 65 + lane] = dist2_u16(~mask, lane);    // d_in^2  (1D)
        }
        __syncthreads();
        int combo = b * 3 + c - 1;
        size_t oA = (size_t)combo * NVOX + (size_t)d * 64;
        size_t oB = (size_t)(combo + 12) * NVOX + (size_t)d * 64;
        for (int w = wid; w < 64; w += 8) {
            bufA[oA + (size_t)w * 4096 + lane] = tA[lane * 65 + w];
            bufA[oB + (size_t)w * 4096 + lane] = tB[lane * 65 + w];
        }
        __syncthreads();
    }
}

// =====================================================================
// K2: block = (combo, w). Loads the two (d,h) planes (out/in) contiguously,
// runs min-plus along H then D in LDS with an EXACT early-exit outward scan
// (stop when dk^2 >= best: all further candidates are >= dk^2), then reduces
// (sqrt(dout2)-sqrt(din2)) * prob_c with coalesced bf16 prob reads.
// =====================================================================
__global__ __launch_bounds__(512) void k2_edt23_sdf(
    const unsigned short* __restrict__ bufA, const unsigned short* __restrict__ probsT,
    float* __restrict__ part_bound) {
    __shared__ float pl[2][64 * 65];
    __shared__ float sredb[8];
    int blk = blockIdx.x;
    int combo = blk >> 6, w = blk & 63;
    int t = threadIdx.x, lane = t & 63, wid = t >> 6;

    for (int v = 0; v < 2; ++v) {
        const unsigned short* src = bufA + (size_t)(combo + 12 * v) * NVOX + (size_t)w * 4096;
        for (int i = 0; i < 8; ++i) {
            int e = t + 512 * i;                     // e = d*64 + h
            unsigned short u = src[e];
            pl[v][e + (e >> 6)] = (u == 0xFFFFu) ? BIGF : (float)u;   // lds[d*65+h]
        }
    }
    __syncthreads();

    // pass along H: wave owns rows d = wid*8+r, lane = h.
    // Outward scan with exact wave-uniform early exit. Index clamp is safe:
    // clamped candidate f[0]+dk^2 upper-bounds the already-visited f[0]+h^2.
    for (int v = 0; v < 2; ++v) {
        for (int r = 0; r < 8; ++r) {
            int dd_ = wid * 8 + r;
            float* row = &pl[v][dd_ * 65];
            float best = row[lane];                  // dk = 0
            for (int dk = 1; dk < 64; ++dk) {
                float d2 = (float)(dk * dk);
                if (__all(d2 >= best)) break;
                int hl = lane - dk; hl = hl < 0 ? 0 : hl;
                int hr = lane + dk; hr = hr > 63 ? 63 : hr;
                best = fminf(fminf(best, row[hl] + d2), row[hr] + d2);
            }
            row[lane] = best;   // wave-lockstep: all reads of this row are done
        }
    }
    __syncthreads();
    // pass along D: wave owns columns h = wid*8+r, lane = d (stride-65: conflict-free)
    for (int v = 0; v < 2; ++v) {
        for (int r = 0; r < 8; ++r) {
            int h = wid * 8 + r;
            float* col = &pl[v][h];
            float best = col[lane * 65];             // dk = 0
            for (int dk = 1; dk < 64; ++dk) {
                float d2 = (float)(dk * dk);
                if (__all(d2 >= best)) break;
                int dl = lane - dk; dl = dl < 0 ? 0 : dl;
                int dr = lane + dk; dr = dr > 63 ? 63 : dr;
                best = fminf(fminf(best, col[dl * 65] + d2), col[dr * 65] + d2);
            }
            col[lane * 65] = best;
        }
    }
    __syncthreads();

    const unsigned short* pp = probsT + (size_t)combo * NVOX + (size_t)w * 4096;
    float acc = 0.0f;
    for (int i = 0; i < 8; ++i) {
        int e = t + 512 * i;
        int li = e + (e >> 6);
        float sdf = sqrtf(pl[0][li]) - sqrtf(pl[1][li]);
        acc += sdf * bf2f(pp[e]);
    }
    #pragma unroll
    for (int o = 32; o > 0; o >>= 1) acc += __shfl_down(acc, o);
    if (lane == 0) sredb[wid] = acc;
    __syncthreads();
    if (t == 0) {
        float s = 0.0f;
        for (int j = 0; j < 8; ++j) s += sredb[j];
        part_bound[blk] = s;
    }
}

// =====================================================================
// K3: single block. Reduce partials (f64), apply empty/full-mask guards,
// assemble the scalar loss.
// =====================================================================
__global__ __launch_bounds__(1024) void k3_final(
    const float* __restrict__ part_stats, const float* __restrict__ part_bound,
    float* __restrict__ out) {
    __shared__ double S[13 * 4];
    __shared__ double BND[12];
    int t = threadIdx.x, lane = t & 63, wid = t >> 6;

    if (t < 256) {              // waves 0..3 <-> b; 64 d-blocks per b
        for (int k = 0; k < 13; ++k) {
            float v = part_stats[k * 256 + t];
            #pragma unroll
            for (int o = 32; o > 0; o >>= 1) v += __shfl_down(v, o);
            if (lane == 0) S[k * 4 + wid] = (double)v;
        }
    }
    __syncthreads();
    if (t < 768) {              // wave id = combo (64 w-entries each)
        float v = part_bound[t];
        #pragma unroll
        for (int o = 32; o > 0; o >>= 1) v += __shfl_down(v, o);
        if (lane == 0) BND[wid] = (double)v;
    }
    __syncthreads();
    if (t == 0) {
        const double NV = (double)NVOX;
        double dice_sum = 0.0;
        for (int b = 0; b < 4; ++b)
            for (int c = 0; c < 4; ++c) {
                double inter = S[c * 4 + b];
                double un    = S[(4 + c) * 4 + b] + S[(8 + c) * 4 + b];
                dice_sum += (2.0 * inter + 1e-5) / (un + 1e-5);
            }
        double l_dice = 1.0 - dice_sum / 16.0;
        double l_ce = (S[48] + S[49] + S[50] + S[51]) / (4.0 * NV);
        double lb = 0.0;
        for (int combo = 0; combo < 12; ++combo) {
            int b = combo / 3, c = combo % 3 + 1;
            double cnt = S[(8 + c) * 4 + b];
            double s;
            if (cnt == 0.0)      s =  S[(4 + c) * 4 + b];   // sdf == +1 everywhere
            else if (cnt == NV)  s = -S[(4 + c) * 4 + b];   // sdf == -1 everywhere
            else                 s =  BND[combo];
            lb += s / NV;
        }
        lb /= 12.0;
        out[0] = (float)(l_dice + l_ce + 0.01 * lb);
    }
}

extern "C" void kernel_launch(void* const* d_in, const int* in_sizes, int n_in,
                              void* d_out, int out_size, void* d_ws, size_t ws_size,
                              hipStream_t stream) {
    const float* preds   = (const float*)d_in[0];
    const int*   targets = (const int*)d_in[1];
    float* out = (float*)d_out;

    // workspace: bufA u16 (12.6 MB) | probsT bf16 (6.3 MB) | partials (~16 KB)
    unsigned short* bufA   = (unsigned short*)d_ws;
    unsigned short* probsT = bufA + (size_t)24 * NVOX;
    float* part_stats = (float*)(probsT + (size_t)12 * NVOX);
    float* part_bound = part_stats + 13 * 256;

    k1_stats_edt1<<<256, 512, 0, stream>>>(preds, targets, bufA, probsT, part_stats);
    k2_edt23_sdf<<<768, 512, 0, stream>>>(bufA, probsT, part_bound);
    k3_final<<<1, 1024, 0, stream>>>(part_stats, part_bound, out);
}